// Round 4
// baseline (420.223 us; speedup 1.0000x reference)
//
#include <hip/hip_runtime.h>

#define BB 1024
#define TT 512
#define CC 41

__global__ __launch_bounds__(64) void crf_viterbi_kernel(
    const float* __restrict__ x,
    const float* __restrict__ start_t,
    const float* __restrict__ end_t,
    const float* __restrict__ trans,
    int* __restrict__ out)   // harness reads out_size int32 elements
{
    __shared__ float score_lds[CC];
    __shared__ unsigned char bp_lds[(TT - 1) * CC];
    __shared__ int tags_lds[TT];

    const int b = blockIdx.x;
    const int lane = threadIdx.x;
    const bool active = lane < CC;
    const int c = active ? lane : (CC - 1);   // clamp inactive lanes for safe loads

    // Preload transitions column c into registers: trans_reg[p] = trans[p][c].
    // For fixed p, lanes read consecutive addresses -> coalesced.
    float trans_reg[CC];
    #pragma unroll
    for (int p = 0; p < CC; ++p) trans_reg[p] = trans[p * CC + c];

    const float* xb = x + (size_t)b * TT * CC;

    // t = 0: score0 = start_transitions + x[:,0]   (exact ref op order)
    float myscore = start_t[c] + xb[c];

    for (int t = 1; t < TT; ++t) {
        if (active) score_lds[lane] = myscore;
        __syncthreads();

        const float emit = xb[t * CC + c];

        // p = 0 seed (first-occurrence argmax semantics via strict >)
        float best;
        int bp;
        {
            float tmp = score_lds[0] + trans_reg[0];
            best = tmp + emit;
            bp = 0;
        }
        #pragma unroll
        for (int p = 1; p < CC; ++p) {
            float tmp = score_lds[p] + trans_reg[p];   // (score + trans)
            float cand = tmp + emit;                   // + emit  (ref op order)
            if (cand > best) { best = cand; bp = p; }  // strict > = first max
        }

        myscore = best;
        if (active) bp_lds[(t - 1) * CC + lane] = (unsigned char)bp;
        __syncthreads();
    }

    // final = score + end_transitions
    if (active) score_lds[lane] = myscore + end_t[c];
    __syncthreads();

    if (lane == 0) {
        // argmax over tags, first occurrence
        float bestv = score_lds[0];
        int tag = 0;
        for (int i = 1; i < CC; ++i) {
            if (score_lds[i] > bestv) { bestv = score_lds[i]; tag = i; }
        }
        tags_lds[TT - 1] = tag;
        // backtrack: tag_{t-1} = bp[t-1][tag_t]
        for (int t = TT - 1; t >= 1; --t) {
            tag = (int)bp_lds[(t - 1) * CC + tag];
            tags_lds[t - 1] = tag;
        }
    }
    __syncthreads();

    // coalesced output write: one int32 per tag, exactly out_size elements
    int* ob = out + (size_t)b * TT;
    for (int i = lane; i < TT; i += 64) ob[i] = tags_lds[i];
}

extern "C" void kernel_launch(void* const* d_in, const int* in_sizes, int n_in,
                              void* d_out, int out_size, void* d_ws, size_t ws_size,
                              hipStream_t stream) {
    (void)in_sizes; (void)n_in; (void)d_ws; (void)ws_size; (void)out_size;
    const float* x       = (const float*)d_in[0];
    const float* start_t = (const float*)d_in[1];
    const float* end_t   = (const float*)d_in[2];
    const float* trans   = (const float*)d_in[3];
    int* out = (int*)d_out;

    crf_viterbi_kernel<<<dim3(BB), dim3(64), 0, stream>>>(x, start_t, end_t, trans, out);
}

// Round 6
// 315.883 us; speedup vs baseline: 1.3303x; 1.3303x over previous
//
#include <hip/hip_runtime.h>

#define BB 1024
#define TT 512
#define CC 41
#define CP 44   // padded score row: 44 floats = 176 B = 11 x float4 (16B aligned)

__global__ __launch_bounds__(64) void crf_viterbi_kernel(
    const float* __restrict__ x,
    const float* __restrict__ start_t,
    const float* __restrict__ end_t,
    const float* __restrict__ trans,
    int* __restrict__ out)   // harness reads out_size int32 elements
{
    __shared__ __align__(16) float sbuf[2][CP];
    __shared__ unsigned char bp_lds[(TT - 1) * CC];
    __shared__ int tags_lds[TT];

    const int b = blockIdx.x;
    const int lane = threadIdx.x;
    const bool active = lane < CC;
    const int c = active ? lane : (CC - 1);   // clamp inactive lanes for safe loads

    // trans column c in registers (coalesced loads: lanes contiguous per p)
    float trans_reg[CC];
    #pragma unroll
    for (int p = 0; p < CC; ++p) trans_reg[p] = trans[p * CC + c];

    const float* xb = x + (size_t)b * TT * CC;

    // t = 0: score0 = start_transitions + x[:,0]   (exact ref op order)
    float myscore = start_t[c] + xb[c];
    if (active) sbuf[0][lane] = myscore;

    // 2-deep emit prefetch pipeline
    float emit_cur = xb[1 * CC + c];   // for t=1
    float emit_nxt = xb[2 * CC + c];   // for t=2
    __syncthreads();

    int cur = 0;
    for (int t = 1; t < TT; ++t) {
        // prefetch emissions for t+2 (clamped; duplicate load is harmless)
        const int tf = (t + 2 < TT) ? (t + 2) : (TT - 1);
        const float emit_fut = xb[(size_t)tf * CC + c];

        // scores of step t-1: 11 x ds_read_b128 (uniform addr -> broadcast)
        float s[CP];
        const float4* srow = (const float4*)sbuf[cur];
        #pragma unroll
        for (int k = 0; k < CP / 4; ++k) {
            const float4 q = srow[k];
            s[4 * k + 0] = q.x; s[4 * k + 1] = q.y;
            s[4 * k + 2] = q.z; s[4 * k + 3] = q.w;
        }

        // candidates: exact ref op order (score + trans) + emit; all independent
        float v[CC];
        int  ix[CC];
        #pragma unroll
        for (int p = 0; p < CC; ++p) {
            v[p]  = (s[p] + trans_reg[p]) + emit_cur;
            ix[p] = p;
        }

        // Segment-tree argmax over contiguous blocks: at every combine, all
        // original indices in the left (kept) slot are < all in the right
        // slot, so strict-> keep-left == jnp.argmax first-occurrence.
        // 40 combines, depth 6.
#define COMBINE(i, j) do { \
            if (v[(j)] > v[(i)]) { v[(i)] = v[(j)]; ix[(i)] = ix[(j)]; } \
        } while (0)
        #pragma unroll
        for (int i = 0; i < 20; ++i) COMBINE(2 * i, 2 * i + 1);   // [2i,2i+1]
        #pragma unroll
        for (int i = 0; i < 10; ++i) COMBINE(4 * i, 4 * i + 2);   // [4i..4i+3]
        #pragma unroll
        for (int i = 0; i < 5; ++i)  COMBINE(8 * i, 8 * i + 4);   // [8i..8i+7]
        COMBINE(0, 8);    // [0..15]
        COMBINE(16, 24);  // [16..31]
        COMBINE(0, 16);   // [0..31]
        COMBINE(32, 40);  // [32..40]
        COMBINE(0, 32);   // [0..40]
#undef COMBINE

        myscore = v[0];
        if (active) {
            sbuf[cur ^ 1][lane] = myscore;                 // double buffer: no 2nd barrier
            bp_lds[(t - 1) * CC + lane] = (unsigned char)ix[0];
        }
        __syncthreads();
        cur ^= 1;

        emit_cur = emit_nxt;
        emit_nxt = emit_fut;
    }

    // final = score + end_transitions   (exact ref op order)
    if (active) sbuf[cur][lane] = myscore + end_t[c];
    __syncthreads();

    if (lane == 0) {
        // argmax over tags, first occurrence
        float bestv = sbuf[cur][0];
        int tag = 0;
        for (int i = 1; i < CC; ++i) {
            if (sbuf[cur][i] > bestv) { bestv = sbuf[cur][i]; tag = i; }
        }
        tags_lds[TT - 1] = tag;
        // backtrack: tag_{t-1} = bp[t-1][tag_t]
        for (int t = TT - 1; t >= 1; --t) {
            tag = (int)bp_lds[(t - 1) * CC + tag];
            tags_lds[t - 1] = tag;
        }
    }
    __syncthreads();

    // coalesced output write: one int32 per tag
    int* ob = out + (size_t)b * TT;
    for (int i = lane; i < TT; i += 64) ob[i] = tags_lds[i];
}

extern "C" void kernel_launch(void* const* d_in, const int* in_sizes, int n_in,
                              void* d_out, int out_size, void* d_ws, size_t ws_size,
                              hipStream_t stream) {
    (void)in_sizes; (void)n_in; (void)d_ws; (void)ws_size; (void)out_size;
    const float* x       = (const float*)d_in[0];
    const float* start_t = (const float*)d_in[1];
    const float* end_t   = (const float*)d_in[2];
    const float* trans   = (const float*)d_in[3];
    int* out = (int*)d_out;

    crf_viterbi_kernel<<<dim3(BB), dim3(64), 0, stream>>>(x, start_t, end_t, trans, out);
}

// Round 7
// 261.638 us; speedup vs baseline: 1.6061x; 1.2073x over previous
//
#include <hip/hip_runtime.h>

#define BB 1024
#define TT 512
#define CC 41

__global__ __launch_bounds__(64) void crf_viterbi_kernel(
    const float* __restrict__ x,
    const float* __restrict__ start_t,
    const float* __restrict__ end_t,
    const float* __restrict__ trans,
    int* __restrict__ out)   // harness reads out_size int32 elements
{
    __shared__ unsigned char bp_lds[(TT - 1) * CC];
    __shared__ int tags_lds[TT];

    const int b = blockIdx.x;
    const int lane = threadIdx.x;
    const bool active = lane < CC;
    const int c = active ? lane : (CC - 1);   // clamp inactive lanes for safe loads

    // trans column c in registers (coalesced loads: lanes contiguous per p)
    float trans_reg[CC];
    #pragma unroll
    for (int p = 0; p < CC; ++p) trans_reg[p] = trans[p * CC + c];

    const float* xb = x + (size_t)b * TT * CC;

    // t = 0: score0 = start_transitions + x[:,0]   (exact ref op order)
    float myscore = start_t[c] + xb[c];

    // 2-deep emit prefetch pipeline
    float emit_cur = xb[1 * CC + c];   // for t=1
    float emit_nxt = xb[2 * CC + c];   // for t=2

    for (int t = 1; t < TT; ++t) {
        // prefetch emissions for t+2 (clamped; duplicate load is harmless)
        const int tf = (t + 2 < TT) ? (t + 2) : (TT - 1);
        const float emit_fut = xb[(size_t)tf * CC + c];

        // Broadcast previous scores via readlane (no LDS, no barrier):
        // score[p] lives in lane p's myscore. Candidates keep exact ref
        // op order: (score + trans) + emit. All 41 are independent.
        float v[CC];
        int  ix[CC];
        #pragma unroll
        for (int p = 0; p < CC; ++p) {
            const float sp = __int_as_float(
                __builtin_amdgcn_readlane(__float_as_int(myscore), p));
            v[p]  = (sp + trans_reg[p]) + emit_cur;
            ix[p] = p;
        }

        // Segment-tree argmax over contiguous blocks: at every combine, all
        // original indices in the left (kept) slot are < all in the right
        // slot, so strict-> keep-left == jnp.argmax first-occurrence.
#define COMBINE(i, j) do { \
            if (v[(j)] > v[(i)]) { v[(i)] = v[(j)]; ix[(i)] = ix[(j)]; } \
        } while (0)
        #pragma unroll
        for (int i = 0; i < 20; ++i) COMBINE(2 * i, 2 * i + 1);   // [2i,2i+1]
        #pragma unroll
        for (int i = 0; i < 10; ++i) COMBINE(4 * i, 4 * i + 2);   // [4i..4i+3]
        #pragma unroll
        for (int i = 0; i < 5; ++i)  COMBINE(8 * i, 8 * i + 4);   // [8i..8i+7]
        COMBINE(0, 8);    // [0..15]
        COMBINE(16, 24);  // [16..31]
        COMBINE(0, 16);   // [0..31]
        COMBINE(32, 40);  // [32..40]
        COMBINE(0, 32);   // [0..40]
#undef COMBINE

        myscore = v[0];
        if (active) bp_lds[(t - 1) * CC + lane] = (unsigned char)ix[0];

        emit_cur = emit_nxt;
        emit_nxt = emit_fut;
    }

    // final = score + end_transitions   (exact ref op order)
    const float fin = myscore + end_t[c];

    // Final argmax over tags (first occurrence), computed uniformly by all
    // lanes via readlane — one-time cost, no LDS needed.
    float bestv = __int_as_float(__builtin_amdgcn_readlane(__float_as_int(fin), 0));
    int tag = 0;
    #pragma unroll
    for (int i = 1; i < CC; ++i) {
        const float vi = __int_as_float(
            __builtin_amdgcn_readlane(__float_as_int(fin), i));
        if (vi > bestv) { bestv = vi; tag = i; }
    }

    __syncthreads();   // bp_lds writes -> lane-0 reads (cheap: 1 wave/block)

    if (lane == 0) {
        tags_lds[TT - 1] = tag;
        int tg = tag;
        // backtrack: tag_{t-1} = bp[t-1][tag_t]
        for (int t = TT - 1; t >= 1; --t) {
            tg = (int)bp_lds[(t - 1) * CC + tg];
            tags_lds[t - 1] = tg;
        }
    }
    __syncthreads();

    // coalesced output write: one int32 per tag
    int* ob = out + (size_t)b * TT;
    for (int i = lane; i < TT; i += 64) ob[i] = tags_lds[i];
}

extern "C" void kernel_launch(void* const* d_in, const int* in_sizes, int n_in,
                              void* d_out, int out_size, void* d_ws, size_t ws_size,
                              hipStream_t stream) {
    (void)in_sizes; (void)n_in; (void)d_ws; (void)ws_size; (void)out_size;
    const float* x       = (const float*)d_in[0];
    const float* start_t = (const float*)d_in[1];
    const float* end_t   = (const float*)d_in[2];
    const float* trans   = (const float*)d_in[3];
    int* out = (int*)d_out;

    crf_viterbi_kernel<<<dim3(BB), dim3(64), 0, stream>>>(x, start_t, end_t, trans, out);
}